// Round 21
// baseline (495.834 us; speedup 1.0000x reference)
//
#include <hip/hip_runtime.h>
#include <hip/hip_bf16.h>
#include <math.h>

#define DIMC 256
#define INNERC 128
#define HEADSC 4
#define DHC 32
#define QKVC 384

typedef __attribute__((ext_vector_type(8))) short bf16frag;   // 8 bf16 = 4 VGPRs
typedef __attribute__((ext_vector_type(4))) float f32x4;

__device__ __forceinline__ float gelu_exact(float x) {
    return 0.5f * x * (1.0f + erff(x * 0.70710678118654752f));
}

__device__ __forceinline__ float b2f(short s) {
    return __uint_as_float(((unsigned)(unsigned short)s) << 16);
}

__device__ __forceinline__ void gload_lds16(const void* g, void* l) {
    __builtin_amdgcn_global_load_lds(
        (const __attribute__((address_space(1))) void*)g,
        (__attribute__((address_space(3))) void*)l, 16, 0, 0);
}

// ---------------- LayerNorm: one WAVE per row, no barriers ----------------
__global__ __launch_bounds__(256)
void ln_kernel(const float* __restrict__ x, const float* __restrict__ g,
               const float* __restrict__ b, __hip_bfloat16* __restrict__ out,
               int N)
{
    int row = blockIdx.x * 4 + (threadIdx.x >> 6);
    if (row >= N) return;
    int lane = threadIdx.x & 63;
    float4 v = *(const float4*)(x + (size_t)row * DIMC + lane * 4);
    float s = v.x + v.y + v.z + v.w;
    float s2 = v.x * v.x + v.y * v.y + v.z * v.z + v.w * v.w;
#pragma unroll
    for (int off = 32; off; off >>= 1) {
        s += __shfl_xor(s, off);
        s2 += __shfl_xor(s2, off);
    }
    float mean = s * (1.f / DIMC);
    float var = s2 * (1.f / DIMC) - mean * mean;
    float rs = rsqrtf(var + 1e-5f);
    float4 gv = *(const float4*)(g + lane * 4);
    float4 bv = *(const float4*)(b + lane * 4);
    __hip_bfloat16 o[4];
    o[0] = __float2bfloat16((v.x - mean) * rs * gv.x + bv.x);
    o[1] = __float2bfloat16((v.y - mean) * rs * gv.y + bv.y);
    o[2] = __float2bfloat16((v.z - mean) * rs * gv.z + bv.z);
    o[3] = __float2bfloat16((v.w - mean) * rs * gv.w + bv.w);
    *(short4*)(out + (size_t)row * DIMC + lane * 4) = *(short4*)o;
}

// ---------------- unified weight prep: one kernel, all conversions ----------
__global__ __launch_bounds__(256)
void prep_kernel(const float* __restrict__ wq, const float* __restrict__ wk,
                 const float* __restrict__ wv, const float* __restrict__ bq,
                 const float* __restrict__ bk, const float* __restrict__ bv,
                 const float* __restrict__ wo, const float* __restrict__ w1,
                 const float* __restrict__ w2,
                 __hip_bfloat16* __restrict__ wqkvB, float* __restrict__ bqkvF,
                 __hip_bfloat16* __restrict__ woB,
                 __hip_bfloat16* __restrict__ w1B,
                 __hip_bfloat16* __restrict__ w2B)
{
    int task = blockIdx.x;
    int t = threadIdx.x;
    if (task < 1536) {
        int l = task / QKVC, c = task % QKVC;
        int which = c >> 7, cc = c & 127;
        const float* srcw = which == 0 ? wq : which == 1 ? wk : wv;
        const float* srcb = which == 0 ? bq : which == 1 ? bk : bv;
        srcw += ((size_t)l * INNERC + cc) * DIMC;
        wqkvB[(size_t)task * DIMC + t] = __float2bfloat16(srcw[t]);
        if (t == 0) bqkvF[task] = srcb[l * INNERC + cc];
        return;
    }
    task -= 1536;
    const float* src;
    __hip_bfloat16* dst;
    if (task < 512)       { src = wo; dst = woB; }
    else if (task < 4608) { task -= 512;  src = w1; dst = w1B; }
    else                  { task -= 4608; src = w2; dst = w2B; }
    size_t idx = (size_t)task * 256 + t;
    dst[idx] = __float2bfloat16(src[idx]);
}

// ---------------- MFMA GEMM v9: templated BM + pipeline DEPTH ---------------
// dbuf/tribuf + counted vmcnt, hoisted pointers, setprio, LDS-staged epilogue.
// DEPTH=2: prefetch 1 tile ahead (shallow-K GEMMs).
// DEPTH=3: prefetch 2 tiles ahead (FF2, 16 K-steps) — T4 deep pipeline:
//          vmcnt(2*loads) keeps two tiles' loads in flight across barriers.
// EPI: 0 = bias -> bf16; 1 = bias+gelu -> bf16; 2 = bias+res -> fp32.
template<int EPI, int BM, int DEPTH>
__global__ __launch_bounds__(512)
void mfma_gemm(const __hip_bfloat16* __restrict__ A,
               const __hip_bfloat16* __restrict__ W,
               const float* __restrict__ bias, const float* __restrict__ res,
               void* __restrict__ Cout, int M, int K, int OUT,
               int mtiles, int ntiles)
{
    constexpr int ASZ = BM * 128;           // one A buf
    constexpr int WSZ = 128 * 128;          // one W buf (16KB)
    constexpr int EPAD = 132;               // fp32 tile row stride (floats)
    constexpr int KSZ = DEPTH * (ASZ + WSZ);
    constexpr int ESZ = BM * EPAD * 4;
    constexpr int LDSZ = (KSZ > ESZ) ? KSZ : ESZ;
    constexpr int MFR = BM / 32;            // acc row-frags per wave (4 or 2)
    constexpr int ALD = (BM * 8) / 512;     // A loads/thread (2 or 1)
    constexpr int TLD = ALD + 2;            // total loads/thread per tile
    __shared__ char lds[LDSZ];

    int nwg = mtiles * ntiles;
    int orig = blockIdx.x;
    int q = nwg >> 3, r = nwg & 7;
    int xcd = orig & 7, loc = orig >> 3;
    int wgid = (xcd < r ? xcd * (q + 1) : r * (q + 1) + (xcd - r) * q) + loc;
    int bm = (wgid / ntiles) * BM;
    int bn = (wgid % ntiles) * 128;

    int tid = threadIdx.x;
    int lane = tid & 63;
    int w = tid >> 6;                        // 0..7
    int wr = w >> 2, wc = w & 3;             // 2 x 4 wave grid
    int l15 = lane & 15, l4 = lane >> 4;

    // ---- hoisted staging addresses (computed once) ----
    const char* aSrc[ALD];
    const char* wSrc[2];
    int aOff[ALD], wOff[2];
#pragma unroll
    for (int it = 0; it < ALD; ++it) {
        int chunk = it * 512 + tid;
        int rr = chunk >> 3;
        int sc = (chunk & 7) ^ (rr & 7);
        int grow = min(bm + rr, M - 1);      // clamp: ALWAYS issue
        aSrc[it] = (const char*)A + ((size_t)grow * K) * 2 + sc * 16;
        aOff[it] = chunk * 16;
    }
#pragma unroll
    for (int it = 0; it < 2; ++it) {
        int chunk = it * 512 + tid;
        int rr = chunk >> 3;
        int sc = (chunk & 7) ^ (rr & 7);
        wSrc[it] = (const char*)W + ((size_t)(bn + rr) * K) * 2 + sc * 16;
        wOff[it] = chunk * 16;
    }

    f32x4 acc[MFR][2] = {};

    auto stage = [&](int b) {               // must be called in K-order
        char* Asb = lds + b * (ASZ + WSZ);
        char* Wsb = Asb + ASZ;
#pragma unroll
        for (int it = 0; it < ALD; ++it) {
            gload_lds16(aSrc[it], Asb + aOff[it]);
            aSrc[it] += 128;                 // 64 bf16 = one K-step
        }
#pragma unroll
        for (int it = 0; it < 2; ++it) {
            gload_lds16(wSrc[it], Wsb + wOff[it]);
            wSrc[it] += 128;
        }
    };

    int nk = K >> 6;
    stage(0);
    if constexpr (DEPTH == 3) stage(1);
    for (int t = 0; t < nk; ++t) {
        int cur = t % DEPTH;
        if constexpr (DEPTH == 2) {
            if (t + 1 < nk) {
                stage((t + 1) % DEPTH);
                asm volatile("s_waitcnt vmcnt(%0)" :: "i"(TLD) : "memory");
            } else {
                asm volatile("s_waitcnt vmcnt(0)" ::: "memory");
            }
        } else {                             // DEPTH == 3
            if (t + 2 < nk) {
                stage((t + 2) % DEPTH);
                asm volatile("s_waitcnt vmcnt(%0)" :: "i"(2 * TLD) : "memory");
            } else if (t + 1 < nk) {
                asm volatile("s_waitcnt vmcnt(%0)" :: "i"(TLD) : "memory");
            } else {
                asm volatile("s_waitcnt vmcnt(0)" ::: "memory");
            }
        }
        __builtin_amdgcn_s_barrier();                    // tile t visible
        char* As = lds + cur * (ASZ + WSZ);
        char* Ws = As + ASZ;
#pragma unroll
        for (int s = 0; s < 2; ++s) {
            bf16frag af[MFR], bfr[2];
            int kb = s * 64 + (l4 << 4);
#pragma unroll
            for (int m = 0; m < MFR; ++m) {
                int ar = wr * (BM / 2) + m * 16 + l15;
                af[m] = *(const bf16frag*)(As + ar * 128 + (kb ^ ((ar & 7) << 4)));
            }
#pragma unroll
            for (int n = 0; n < 2; ++n) {
                int br = wc * 32 + n * 16 + l15;
                bfr[n] = *(const bf16frag*)(Ws + br * 128 + (kb ^ ((br & 7) << 4)));
            }
            __builtin_amdgcn_s_setprio(1);
#pragma unroll
            for (int m = 0; m < MFR; ++m)
#pragma unroll
                for (int n = 0; n < 2; ++n)
                    acc[m][n] = __builtin_amdgcn_mfma_f32_16x16x32_bf16(
                        af[m], bfr[n], acc[m][n], 0, 0, 0);
            __builtin_amdgcn_s_setprio(0);
        }
        __builtin_amdgcn_s_barrier();                    // WAR on buf
    }

    // ---- epilogue: stage fp32 tile to LDS, then coalesced writes ----
    float* tile = (float*)lds;               // [BM][EPAD]
    __syncthreads();                          // all LDS K-loop reads done
#pragma unroll
    for (int m = 0; m < MFR; ++m)
#pragma unroll
        for (int rr = 0; rr < 4; ++rr) {
            int lrow = wr * (BM / 2) + m * 16 + (l4 << 2) + rr;
#pragma unroll
            for (int n = 0; n < 2; ++n) {
                int lcol = wc * 32 + n * 16 + l15;
                float val = acc[m][n][rr] + bias[bn + lcol];
                if (EPI == 1) val = gelu_exact(val);
                tile[lrow * EPAD + lcol] = val;
            }
        }
    __syncthreads();

    if (EPI == 2) {
        int rp = tid >> 5, c4 = (tid & 31) * 4;
        float* outF = (float*)Cout;
#pragma unroll
        for (int pass = 0; pass < BM / 16; ++pass) {
            int lrow = pass * 16 + rp;
            int grow = bm + lrow;
            if (grow < M) {
                float4 v = *(float4*)&tile[lrow * EPAD + c4];
                const float4 rv = *(const float4*)&res[(size_t)grow * OUT + bn + c4];
                v.x += rv.x; v.y += rv.y; v.z += rv.z; v.w += rv.w;
                *(float4*)&outF[(size_t)grow * OUT + bn + c4] = v;
            }
        }
    } else {
        int rp = tid >> 5, c4 = (tid & 31) * 4;
        __hip_bfloat16* outB = (__hip_bfloat16*)Cout;
#pragma unroll
        for (int pass = 0; pass < BM / 16; ++pass) {
            int lrow = pass * 16 + rp;
            int grow = bm + lrow;
            if (grow < M) {
                float4 v = *(float4*)&tile[lrow * EPAD + c4];
                __hip_bfloat16 o[4];
                o[0] = __float2bfloat16(v.x);
                o[1] = __float2bfloat16(v.y);
                o[2] = __float2bfloat16(v.z);
                o[3] = __float2bfloat16(v.w);
                *(short4*)&outB[(size_t)grow * OUT + bn + c4] = *(short4*)o;
            }
        }
    }
}

// ---------------- CSR build: count + hierarchical scan + scatter ------------
__global__ void count_kernel(const int* __restrict__ dst, int* __restrict__ count, int E)
{
    int e = blockIdx.x * blockDim.x + threadIdx.x;
    if (e < E) atomicAdd(&count[dst[e]], 1);
}

__global__ __launch_bounds__(1024)
void scanA_kernel(const int* __restrict__ count, int* __restrict__ rowptr,
                  int* __restrict__ bsum, int N)
{
    __shared__ int sdata[1024];
    int b = blockIdx.x, t = threadIdx.x;
    int idx = b * 1024 + t;
    int v = (idx < N) ? count[idx] : 0;
    sdata[t] = v;
    __syncthreads();
    for (int off = 1; off < 1024; off <<= 1) {
        int add = (t >= off) ? sdata[t - off] : 0;
        __syncthreads();
        sdata[t] += add;
        __syncthreads();
    }
    if (idx < N) rowptr[idx + 1] = sdata[t];
    if (t == 1023) bsum[b] = sdata[1023];
}

__global__ void scanB_kernel(int* __restrict__ bsum, int nb)
{
    int t = threadIdx.x;
    int v = (t < nb) ? bsum[t] : 0;
#pragma unroll
    for (int off = 1; off < 64; off <<= 1) {
        int u = __shfl_up(v, off);
        if (t >= off) v += u;
    }
    if (t < nb) bsum[t] = v;
}

__global__ __launch_bounds__(1024)
void scanC_kernel(int* __restrict__ rowptr, const int* __restrict__ bsum, int N)
{
    int b = blockIdx.x, t = threadIdx.x;
    int idx = b * 1024 + t;
    if (idx == 0) rowptr[0] = 0;
    if (idx < N && b > 0) rowptr[idx + 1] += bsum[b - 1];
}

__global__ void scatter_kernel(const int* __restrict__ src, const int* __restrict__ dst,
                               const int* __restrict__ rowptr, int* __restrict__ cursor,
                               int* __restrict__ srcperm, int E)
{
    int e = blockIdx.x * blockDim.x + threadIdx.x;
    if (e < E) {
        int d = dst[e];
        int pos = rowptr[d] + atomicAdd(&cursor[d], 1);
        srcperm[pos] = src[e];
    }
}

// ---------------- Attention: wave/node, V-loads hoisted above softmax -------
__global__ __launch_bounds__(256)
void attn_kernel(const __hip_bfloat16* __restrict__ qkv, const int* __restrict__ rowptr,
                 const int* __restrict__ srcperm, __hip_bfloat16* __restrict__ agg,
                 int N)
{
    int wid = (blockIdx.x * 256 + threadIdx.x) >> 6;   // node index
    if (wid >= N) return;
    int lane = threadIdx.x & 63;
    int h = lane >> 4, u = lane & 15;
    int i = wid;
    int beg = rowptr[i], deg = rowptr[i + 1] - beg;
    const short* base = (const short*)qkv;
    const float scale = 0.17677669529663687f; // 1/sqrt(32)

    bf16frag qf[4];
    const short* qr = base + (size_t)i * QKVC + h * 32;
#pragma unroll
    for (int c = 0; c < 4; ++c) qf[c] = *(const bf16frag*)(qr + c * 8);

    float m_run = -3.4e38f, d_run = 0.f;
    float accx = 0.f, accy = 0.f;

    int j = (u < deg) ? srcperm[beg + u] : i;
    bf16frag kf[4];
    {
        const short* kr = base + (size_t)j * QKVC + 128 + h * 32;
#pragma unroll
        for (int c = 0; c < 4; ++c) kf[c] = *(const bf16frag*)(kr + c * 8);
    }

    for (int c0 = 0; c0 < deg; c0 += 16) {
        int cn = min(16, deg - c0);
        bool valid = (u < cn);

        int nxt = c0 + 16 + u;
        int jn = (nxt < deg) ? srcperm[beg + nxt] : i;

        // ---- issue V gathers NOW (addresses need only j) ----
        unsigned vws[16];
#pragma unroll
        for (int e = 0; e < 16; ++e) {
            int je = __shfl(j, h * 16 + e);        // invalid slots -> row i
            vws[e] = *(const unsigned*)(base + (size_t)je * QKVC + 256 + h * 32 + u * 2);
        }

        // ---- issue next chunk's K prefetch ----
        bf16frag kfn[4];
        {
            const short* krn = base + (size_t)jn * QKVC + 128 + h * 32;
#pragma unroll
            for (int c = 0; c < 4; ++c) kfn[c] = *(const bf16frag*)(krn + c * 8);
        }

        // ---- dot (uses prefetched kf) — covers V/K latency ----
        float dot = 0.f;
#pragma unroll
        for (int c = 0; c < 4; ++c)
#pragma unroll
            for (int e = 0; e < 8; ++e)
                dot += b2f(qf[c][e]) * b2f(kf[c][e]);
        float alpha = valid ? dot * scale : -3.4e38f;

        float cm = alpha;
#pragma unroll
        for (int off = 8; off; off >>= 1) cm = fmaxf(cm, __shfl_xor(cm, off));
        float m_new = fmaxf(m_run, cm);
        float rescale = __expf(m_run - m_new);
        float w = valid ? __expf(alpha - m_new) : 0.f;
        float dsum = w;
#pragma unroll
        for (int off = 8; off; off >>= 1) dsum += __shfl_xor(dsum, off);
        d_run = d_run * rescale + dsum;
        m_run = m_new;
        accx *= rescale;
        accy *= rescale;

        float wes[16];
#pragma unroll
        for (int e = 0; e < 16; ++e)
            wes[e] = __shfl(w, h * 16 + e);
#pragma unroll
        for (int e = 0; e < 16; ++e) {
            accx += wes[e] * b2f((short)(vws[e] & 0xffff));
            accy += wes[e] * b2f((short)(vws[e] >> 16));
        }
        j = jn;
#pragma unroll
        for (int c = 0; c < 4; ++c) kf[c] = kfn[c];
    }

    float inv = 1.f / (d_run + 1e-16f);
    __hip_bfloat16* outp = agg + (size_t)i * INNERC + h * 32 + u * 2;
    outp[0] = __float2bfloat16(accx * inv);
    outp[1] = __float2bfloat16(accy * inv);
}

// ---------------- Launch ----------------
extern "C" void kernel_launch(void* const* d_in, const int* in_sizes, int n_in,
                              void* d_out, int out_size, void* d_ws, size_t ws_size,
                              hipStream_t stream)
{
    const float* x    = (const float*)d_in[0];
    const int*   ei   = (const int*)  d_in[1];
    const float* ln1g = (const float*)d_in[2];
    const float* ln1b = (const float*)d_in[3];
    const float* wq   = (const float*)d_in[4];
    const float* bq   = (const float*)d_in[5];
    const float* wk   = (const float*)d_in[6];
    const float* bk   = (const float*)d_in[7];
    const float* wv   = (const float*)d_in[8];
    const float* bv   = (const float*)d_in[9];
    const float* wo   = (const float*)d_in[10];
    const float* bo   = (const float*)d_in[11];
    const float* ln2g = (const float*)d_in[12];
    const float* ln2b = (const float*)d_in[13];
    const float* w1   = (const float*)d_in[14];
    const float* b1   = (const float*)d_in[15];
    const float* w2   = (const float*)d_in[16];
    const float* b2   = (const float*)d_in[17];

    const int N = in_sizes[0] / DIMC;   // 20000
    const int E = in_sizes[1] / 2;      // 320000
    const int* srcIdx = ei;
    const int* dstIdx = ei + E;

    char* p = (char*)d_ws;
    auto alloc = [&](size_t bytes) {
        char* r = p;
        p += (bytes + 255) & ~(size_t)255;
        return r;
    };
    float*          xbuf   = (float*)alloc((size_t)N * DIMC * 4);
    __hip_bfloat16* h      = (__hip_bfloat16*)alloc((size_t)N * DIMC * 2);
    __hip_bfloat16* qkv    = (__hip_bfloat16*)alloc((size_t)N * QKVC * 2);
    __hip_bfloat16* agg    = (__hip_bfloat16*)alloc((size_t)N * INNERC * 2);
    __hip_bfloat16* u      = (__hip_bfloat16*)alloc((size_t)N * 1024 * 2);
    int*            rowptr = (int*)alloc((size_t)(N + 1) * 4);
    int*            cnt    = (int*)alloc((size_t)N * 4);
    int*            bsum   = (int*)alloc((size_t)64 * 4);
    int*            srcperm= (int*)alloc((size_t)E * 4);
    __hip_bfloat16* wqkvB  = (__hip_bfloat16*)alloc((size_t)4 * QKVC * DIMC * 2);
    float*          bqkvF  = (float*)alloc((size_t)4 * QKVC * 4);
    __hip_bfloat16* woB    = (__hip_bfloat16*)alloc((size_t)4 * DIMC * INNERC * 2);
    __hip_bfloat16* w1B    = (__hip_bfloat16*)alloc((size_t)4 * 1024 * DIMC * 2);
    __hip_bfloat16* w2B    = (__hip_bfloat16*)alloc((size_t)4 * DIMC * 1024 * 2);

    // Unified weight prep: 1536 + 512 + 4096 + 4096 = 10240 tasks, 1 launch
    prep_kernel<<<10240, 256, 0, stream>>>(wq, wk, wv, bq, bk, bv, wo, w1, w2,
                                           wqkvB, bqkvF, woB, w1B, w2B);

    // CSR build (hierarchical scan)
    int nb = (N + 1023) / 1024;     // 20
    hipMemsetAsync(cnt, 0, (size_t)N * 4, stream);
    count_kernel<<<(E + 255) / 256, 256, 0, stream>>>(dstIdx, cnt, E);
    scanA_kernel<<<nb, 1024, 0, stream>>>(cnt, rowptr, bsum, N);
    scanB_kernel<<<1, 64, 0, stream>>>(bsum, nb);
    scanC_kernel<<<nb, 1024, 0, stream>>>(rowptr, bsum, N);
    hipMemsetAsync(cnt, 0, (size_t)N * 4, stream);
    scatter_kernel<<<(E + 255) / 256, 256, 0, stream>>>(srcIdx, dstIdx, rowptr, cnt, srcperm, E);

    int mt = (N + 127) / 128;        // 157
    int mt64 = (N + 63) / 64;        // 313
    int lnBlocks = (N + 3) / 4;      // 5000
    int attnBlocks = (N * 64 + 255) / 256;
    for (int l = 0; l < 4; ++l) {
        const float* xin = (l == 0) ? x : xbuf;
        ln_kernel<<<lnBlocks, 256, 0, stream>>>(xin, ln1g + l * DIMC, ln1b + l * DIMC, h, N);
        // QKV: OUT=384, BM=128, depth-2 -> 471 blocks
        mfma_gemm<0, 128, 2><<<mt * 3, 512, 0, stream>>>(
            h, wqkvB + (size_t)l * QKVC * DIMC, bqkvF + l * QKVC, nullptr,
            qkv, N, DIMC, QKVC, mt, 3);
        attn_kernel<<<attnBlocks, 256, 0, stream>>>(qkv, rowptr, srcperm, agg, N);
        // out-proj: OUT=256, K=128, BM=64, depth-2 -> 626 blocks
        mfma_gemm<2, 64, 2><<<mt64 * 2, 512, 0, stream>>>(
            agg, woB + (size_t)l * DIMC * INNERC, bo + l * DIMC, xin,
            xbuf, N, INNERC, DIMC, mt64, 2);
        ln_kernel<<<lnBlocks, 256, 0, stream>>>(xbuf, ln2g + l * DIMC, ln2b + l * DIMC, h, N);
        // FF1: OUT=1024, BM=128, depth-2 -> 1256 blocks
        mfma_gemm<1, 128, 2><<<mt * 8, 512, 0, stream>>>(
            h, w1B + (size_t)l * 1024 * DIMC, b1 + l * 1024, nullptr,
            u, N, DIMC, 1024, mt, 8);
        float* xout = (l == 3) ? (float*)d_out : xbuf;
        // FF2: OUT=256, K=1024, BM=64, DEPTH-3 (16 K-steps, T4 deep pipeline)
        mfma_gemm<2, 64, 3><<<mt64 * 2, 512, 0, stream>>>(
            u, w2B + (size_t)l * DIMC * 1024, b2 + l * DIMC, xbuf,
            xout, N, 1024, DIMC, mt64, 2);
    }
}